// Round 18
// baseline (788.670 us; speedup 1.0000x reference)
//
#include <hip/hip_runtime.h>
#include <hip/hip_bf16.h>

#define PI2F 9.869604401089358f

typedef __attribute__((ext_vector_type(8))) short bf16x8;
typedef __attribute__((ext_vector_type(4))) float f32x4;

#define GLOAD16(g, l) __builtin_amdgcn_global_load_lds( \
    (const __attribute__((address_space(1))) void*)(g), \
    (__attribute__((address_space(3))) void*)(l), 16, 0, 0)

__device__ inline unsigned short f2b(float v) {
    union { float f; unsigned u; } x; x.f = v;
    unsigned r = x.u + 0x7fffu + ((x.u >> 16) & 1u);
    return (unsigned short)(r >> 16);
}

__device__ inline float gelu_tanh(float v) {
    float u = 0.7978845608028654f * (v + 0.044715f * v * v * v);
    float th = 1.f - 2.f / (1.f + __expf(2.f * u));
    return 0.5f * v * (1.f + th);
}

// =============== Kernel A: unfold + separable circular blur + MFMA conv0 + leaky + GN(G=4) =====
__global__ __launch_bounds__(256) void k_blur_conv0(
    const float* __restrict__ img, const float* __restrict__ bfac,
    const float* __restrict__ w0, const float* __restrict__ b0c,
    const float* __restrict__ g1, const float* __restrict__ be1,
    unsigned short* __restrict__ d0)
{
    __shared__ float pa[512], pb[512], hsm[8];
    __shared__ unsigned short pbb[512];
    __shared__ unsigned short w0b[32][72];
    __shared__ float d0s[64 * 33];
    __shared__ float2 gstat[4];
    const int t = threadIdx.x, blk = blockIdx.x;
    const int b = blk >> 9, rem = blk & 511;
    const int zh = rem >> 6, yh = (rem >> 3) & 7, xh = rem & 7;

    #pragma unroll
    for (int i = 0; i < 2; i++) {
        int v = t + 256 * i;
        int z = v >> 6, y = (v >> 3) & 7, x = v & 7;
        pa[v] = img[(((size_t)(b * 8 + zh) * 8 + z) * 64 + yh * 8 + y) * 64 + xh * 8 + x];
    }
    #pragma unroll
    for (int i = 0; i < 8; i++) {
        int idx = i * 256 + t;
        w0b[idx >> 6][idx & 63] = f2b(w0[idx]);
    }
    if (t < 8) {
        float bf = bfac[blk];
        float c = bf * PI2F * (1.0f / 16.0f);
        float gk1 = __expf(-c), gk2 = __expf(-4.f * c), gk3 = __expf(-9.f * c), gk4 = __expf(-16.f * c);
        float d = (float)t;
        float h = 1.f + 2.f * (gk1 * cosf(0.7853981633974483f * d)
                             + gk2 * cosf(1.5707963267948966f * d)
                             + gk3 * cosf(2.356194490192345f * d))
                      + gk4 * cosf(3.141592653589793f * d);
        hsm[t] = 0.125f * h;
    }
    __syncthreads();
    #pragma unroll
    for (int i = 0; i < 2; i++) {
        int v = t + 256 * i; int x = v & 7; int base = v & ~7;
        float s = 0.f;
        #pragma unroll
        for (int m = 0; m < 8; m++) s += hsm[(x - m) & 7] * pa[base + m];
        pb[v] = s;
    }
    __syncthreads();
    #pragma unroll
    for (int i = 0; i < 2; i++) {
        int v = t + 256 * i; int y = (v >> 3) & 7; int base = (v & ~63) | (v & 7);
        float s = 0.f;
        #pragma unroll
        for (int m = 0; m < 8; m++) s += hsm[(y - m) & 7] * pb[base + m * 8];
        pa[v] = s;
    }
    __syncthreads();
    #pragma unroll
    for (int i = 0; i < 2; i++) {
        int v = t + 256 * i; int z = v >> 6; int base = v & 63;
        float s = 0.f;
        #pragma unroll
        for (int m = 0; m < 8; m++) s += hsm[(z - m) & 7] * pa[base + m * 64];
        pb[v] = s;
        pbb[v] = f2b(s);
    }
    __syncthreads();
    const int wid = t >> 6, lane = t & 63;
    const int lr = lane & 15, lk8 = (lane >> 4) * 8;
    {
        const int vox = wid * 16 + lr;
        const int szb = 2 * (vox >> 4) - 1, syb = 2 * ((vox >> 2) & 3) - 1, sxb = 2 * (vox & 3) - 1;
        f32x4 acc0 = {}, acc1 = {};
        #pragma unroll
        for (int ks = 0; ks < 2; ks++) {
            bf16x8 a;
            #pragma unroll
            for (int j = 0; j < 8; j++) {
                int tap = ks * 32 + lk8 + j;
                int sz = szb + (tap >> 4), sy = syb + ((tap >> 2) & 3), sx = sxb + (tap & 3);
                bool ok = (unsigned)sz < 8u && (unsigned)sy < 8u && (unsigned)sx < 8u;
                a[j] = ok ? (short)pbb[sz * 64 + sy * 8 + sx] : (short)0;
            }
            bf16x8 b0 = *(const bf16x8*)&w0b[lr][ks * 32 + lk8];
            bf16x8 b1 = *(const bf16x8*)&w0b[16 + lr][ks * 32 + lk8];
            acc0 = __builtin_amdgcn_mfma_f32_16x16x32_bf16(a, b0, acc0, 0, 0, 0);
            acc1 = __builtin_amdgcn_mfma_f32_16x16x32_bf16(a, b1, acc1, 0, 0, 0);
        }
        const float bA = b0c[lr], bB = b0c[16 + lr];
        #pragma unroll
        for (int r = 0; r < 4; r++) {
            int crow = wid * 16 + (lane >> 4) * 4 + r;
            float v0 = acc0[r] + bA; v0 = v0 >= 0.f ? v0 : 0.2f * v0;
            float v1 = acc1[r] + bB; v1 = v1 >= 0.f ? v1 : 0.2f * v1;
            d0s[crow * 33 + lr] = v0;
            d0s[crow * 33 + 16 + lr] = v1;
        }
    }
    __syncthreads();
    {
        int g = wid;
        float s = 0.f, sq = 0.f;
        #pragma unroll
        for (int cc = 0; cc < 8; cc++) { float v = d0s[lane * 33 + g * 8 + cc]; s += v; sq += v * v; }
        #pragma unroll
        for (int m = 1; m < 64; m <<= 1) { s += __shfl_xor(s, m, 64); sq += __shfl_xor(sq, m, 64); }
        if (lane == 0) {
            float mean = s * (1.f / 512.f);
            float var = sq * (1.f / 512.f) - mean * mean;
            gstat[g] = make_float2(mean, rsqrtf(var + 1e-5f));
        }
    }
    __syncthreads();
    size_t obase = (size_t)blk * 2048;
    #pragma unroll
    for (int i = 0; i < 8; i++) {
        int oi = t + 256 * i;
        int c = oi >> 6, vox = oi & 63;
        float2 st = gstat[oi >> 9];
        d0[obase + oi] = f2b((d0s[vox * 33 + c] - st.x) * st.y * g1[c] + be1[c]);
    }
}

// =============== ONE merged weight-prep kernel ===============
__global__ __launch_bounds__(256) void k_prep_all(
    const float* __restrict__ w1, const float* __restrict__ w2, const float* __restrict__ wu,
    const float* __restrict__ b1c,
    const float* __restrict__ Wq, const float* __restrict__ Wk, const float* __restrict__ Wv,
    const float* __restrict__ bq, const float* __restrict__ bk, const float* __restrict__ bv,
    const float* __restrict__ Wo, const float* __restrict__ W1, const float* __restrict__ W2,
    unsigned short* __restrict__ w1T, unsigned short* __restrict__ w2T,
    unsigned short* __restrict__ wuT, float* __restrict__ b1x,
    unsigned short* __restrict__ WqkvT, float* __restrict__ bqkv,
    unsigned short* __restrict__ WoT, unsigned short* __restrict__ W1T, unsigned short* __restrict__ W2T)
{
    const int blk = blockIdx.x, t = threadIdx.x;
    if (blk < 4096) {
        int idx = blk * 256 + t;
        int n = idx >> 11, k = idx & 2047;
        int oc = n >> 3, vox = n & 7;
        int oz = vox >> 2, oy = (vox >> 1) & 1, ox = vox & 1;
        int ci = k >> 6, sp = k & 63;
        int sz = sp >> 4, sy = (sp >> 2) & 3, sx = sp & 3;
        int kz = sz + 1 - 2 * oz, ky = sy + 1 - 2 * oy, kx = sx + 1 - 2 * ox;
        float v = 0.f;
        if ((unsigned)kz < 4u && (unsigned)ky < 4u && (unsigned)kx < 4u)
            v = w1[(size_t)oc * 2048 + ci * 64 + kz * 16 + ky * 4 + kx];
        w1T[idx] = f2b(v);
    } else if (blk < 4352) {
        int idx = (blk - 4096) * 256 + t;
        int n = idx >> 9, k = idx & 511;
        int ci = k >> 3, v = k & 7;
        int z = v >> 2, y = (v >> 1) & 1, x = v & 1;
        w2T[idx] = f2b(w2[(size_t)n * 4096 + ci * 64 + (z + 1) * 16 + (y + 1) * 4 + (x + 1)]);
    } else if (blk < 4480) {
        int idx = (blk - 4352) * 256 + t;
        wuT[idx] = f2b(wu[idx]);
    } else if (blk < 4482) {
        int idx = (blk - 4480) * 256 + t;
        b1x[idx] = b1c[idx >> 3];
    } else if (blk < 10626) {
        int task = blk - 4482;
        int l = task / 768, n = task % 768;
        int sel = n >> 8, col = n & 255;
        const float* W = sel == 0 ? Wq : sel == 1 ? Wk : Wv;
        const float* bb = sel == 0 ? bq : sel == 1 ? bk : bv;
        WqkvT[((size_t)l * 768 + n) * 256 + t] = f2b(W[(size_t)l * 65536 + (size_t)t * 256 + col]);
        if (t == 0) bqkv[l * 768 + n] = bb[l * 256 + col];
    } else if (blk < 12674) {
        int gid = (blk - 10626) * 256 + t;
        int l = gid >> 16, w = gid & 65535;
        int n = w >> 8, k = w & 255;
        WoT[gid] = f2b(Wo[(size_t)l * 65536 + (size_t)k * 256 + n]);
    } else if (blk < 20866) {
        int gid = (blk - 12674) * 256 + t;
        int l = gid >> 18, w = gid & 262143;
        int n = w >> 8, k = w & 255;
        W1T[gid] = f2b(W1[(size_t)l * 262144 + (size_t)k * 1024 + n]);
    } else {
        int gid = (blk - 20866) * 256 + t;
        int l = gid >> 18, w = gid & 262143;
        int n = w >> 10, k = w & 1023;
        W2T[gid] = f2b(W2[(size_t)l * 262144 + (size_t)k * 256 + n]);
    }
}

// ====== MFMA GEMM 128x128 tile: XCD swizzle + gload_lds + T2 swizzle + dbuf + counted vmcnt ======
// 4 waves in 2x2; per wave 64x64 output (acc[4][4] f32x4). Stage = 4 A + 4 B GLOAD16/wave.
__global__ __launch_bounds__(256) void k_gemm_bf16(
    const unsigned short* __restrict__ A, const unsigned short* __restrict__ WT,
    const float* __restrict__ bias, const float* __restrict__ res,
    void* __restrict__ Cout, int NXB, int N, int K, int act, int obf)
{
    __shared__ unsigned short Ash[2][128][64];
    __shared__ unsigned short Bsh[2][128][64];
    const int t = threadIdx.x;
    const int lb = blockIdx.x;
    const int xcd = lb & 7, j = lb >> 3;
    const int gy = xcd * 8 + j / NXB, gx = j % NXB;
    const int c0 = gx * 128;
    const int r0 = gy * 128;
    const int wid = t >> 6, lane = t & 63;
    const int wr = wid >> 1, wc = wid & 1;
    const int lrow = lane & 15, lk = (lane >> 4) * 8;
    const int xsw = (lrow & 7) << 3;
    const int srcsw = ((lane & 7) ^ (lane >> 3)) << 3;

    auto stage = [&](int k0, int bsel) {
        const unsigned short* ga = A + (size_t)(r0 + wid * 32 + (lane >> 3)) * K + k0 + srcsw;
        unsigned short* la = &Ash[bsel][wid * 32][0];
        #pragma unroll
        for (int i = 0; i < 4; i++)
            GLOAD16(ga + (size_t)(i * 8) * K, la + i * 8 * 64);
        const unsigned short* gb = WT + (size_t)(c0 + wid * 32 + (lane >> 3)) * K + k0 + srcsw;
        unsigned short* lbp = &Bsh[bsel][wid * 32][0];
        #pragma unroll
        for (int i = 0; i < 4; i++)
            GLOAD16(gb + (size_t)(i * 8) * K, lbp + i * 8 * 64);
    };

    f32x4 acc[4][4] = {};
    stage(0, 0);
    int cur = 0;
    for (int k0 = 0; k0 < K; k0 += 64) {
        if (k0 + 64 < K) {
            stage(k0 + 64, cur ^ 1);
            asm volatile("s_waitcnt vmcnt(8)" ::: "memory");
        } else {
            asm volatile("s_waitcnt vmcnt(0)" ::: "memory");
        }
        __builtin_amdgcn_s_barrier();
        __builtin_amdgcn_sched_barrier(0);
        #pragma unroll
        for (int ks = 0; ks < 2; ks++) {
            bf16x8 bfrag[4];
            #pragma unroll
            for (int n = 0; n < 4; n++)
                bfrag[n] = *(const bf16x8*)&Bsh[cur][wc * 64 + n * 16 + lrow][(ks * 32 + lk) ^ xsw];
            #pragma unroll
            for (int m = 0; m < 4; m++) {
                bf16x8 a = *(const bf16x8*)&Ash[cur][wr * 64 + m * 16 + lrow][(ks * 32 + lk) ^ xsw];
                #pragma unroll
                for (int n = 0; n < 4; n++)
                    acc[m][n] = __builtin_amdgcn_mfma_f32_16x16x32_bf16(a, bfrag[n], acc[m][n], 0, 0, 0);
            }
        }
        __builtin_amdgcn_s_barrier();
        cur ^= 1;
    }
    const int rbase = r0 + wr * 64 + (lane >> 4) * 4;
    #pragma unroll
    for (int n = 0; n < 4; n++) {
        const int col = c0 + wc * 64 + n * 16 + lrow;
        const float bv = bias[col];
        #pragma unroll
        for (int m = 0; m < 4; m++) {
            #pragma unroll
            for (int r = 0; r < 4; r++) {
                float v = acc[m][n][r] + bv;
                if (act == 1) v = gelu_tanh(v);
                else if (act == 2) v = v >= 0.f ? v : 0.2f * v;
                size_t off = (size_t)(rbase + m * 16 + r) * N + col;
                if (res) v += res[off];
                if (obf) ((unsigned short*)Cout)[off] = f2b(v);
                else ((float*)Cout)[off] = v;
            }
        }
    }
}

// ====== Fused conv2 GEMM + leaky + row-GN(128) -> bf16 ======
__global__ __launch_bounds__(512) void k_gemm_gn(
    const unsigned short* __restrict__ A, const unsigned short* __restrict__ WT,
    const float* __restrict__ bias, const float* __restrict__ g3, const float* __restrict__ be3,
    unsigned short* __restrict__ out)
{
    __shared__ __align__(16) char smem[23040];
    unsigned short (*Ash)[72] = (unsigned short(*)[72])smem;
    unsigned short (*Bsh)[72] = (unsigned short(*)[72])(smem + 4608);
    float (*vals)[136] = (float(*)[136])smem;
    const int t = threadIdx.x;
    const int r0 = blockIdx.x * 32;
    const int wid = t >> 6, lane = t & 63;
    const int mrow = wid >> 2, colq = wid & 3;
    const int lr = lane & 15, lk8 = (lane >> 4) * 8;
    f32x4 acc[2] = {};
    for (int k0 = 0; k0 < 512; k0 += 64) {
        __syncthreads();
        if (t < 256) {
            int f = t * 8;
            int r = f >> 6, kk = f & 63;
            *(bf16x8*)&Ash[r][kk] = *(const bf16x8*)(A + (size_t)(r0 + r) * 512 + k0 + kk);
        }
        #pragma unroll
        for (int i = 0; i < 2; i++) {
            int f = (i * 512 + t) * 8;
            int r = f >> 6, kk = f & 63;
            *(bf16x8*)&Bsh[r][kk] = *(const bf16x8*)(WT + (size_t)r * 512 + k0 + kk);
        }
        __syncthreads();
        #pragma unroll
        for (int ks = 0; ks < 2; ks++) {
            bf16x8 a = *(const bf16x8*)&Ash[mrow * 16 + lr][ks * 32 + lk8];
            #pragma unroll
            for (int nf = 0; nf < 2; nf++) {
                bf16x8 bb = *(const bf16x8*)&Bsh[colq * 32 + nf * 16 + lr][ks * 32 + lk8];
                acc[nf] = __builtin_amdgcn_mfma_f32_16x16x32_bf16(a, bb, acc[nf], 0, 0, 0);
            }
        }
    }
    __syncthreads();
    #pragma unroll
    for (int nf = 0; nf < 2; nf++) {
        int col = colq * 32 + nf * 16 + lr;
        float bv = bias[col];
        #pragma unroll
        for (int r = 0; r < 4; r++) {
            int row = mrow * 16 + (lane >> 4) * 4 + r;
            float v = acc[nf][r] + bv;
            vals[row][col] = v >= 0.f ? v : 0.2f * v;
        }
    }
    __syncthreads();
    const int row = t >> 4, cc0 = (t & 15) * 8;
    float s = 0.f, sq = 0.f;
    #pragma unroll
    for (int j = 0; j < 8; j++) {
        float v = vals[row][cc0 + j];
        s += v; sq += v * v;
    }
    s += __shfl_xor(s, 1); sq += __shfl_xor(sq, 1);
    s += __shfl_xor(s, 2); sq += __shfl_xor(sq, 2);
    s += __shfl_xor(s, 4); sq += __shfl_xor(sq, 4);
    s += __shfl_xor(s, 8); sq += __shfl_xor(sq, 8);
    float mean = s * (1.f / 128.f);
    float rs = rsqrtf(sq * (1.f / 128.f) - mean * mean + 1e-5f);
    ushort4 o[2];
    #pragma unroll
    for (int h = 0; h < 2; h++) {
        #pragma unroll
        for (int j = 0; j < 4; j++) {
            int col = cc0 + h * 4 + j;
            float v = (vals[row][col] - mean) * rs * g3[col] + be3[col];
            ((unsigned short*)&o[h])[j] = f2b(v);
        }
    }
    *(ushort4*)(out + (size_t)(r0 + row) * 128 + cc0) = o[0];
    *(ushort4*)(out + (size_t)(r0 + row) * 128 + cc0 + 4) = o[1];
}

// ====== Fused GEMM + residual + row-LN (Wo and W2), dbuf + counted vmcnt ======
__global__ __launch_bounds__(512) void k_gemm_ln(
    const unsigned short* __restrict__ A, const unsigned short* __restrict__ WT,
    const float* __restrict__ bias, const float* __restrict__ res,
    const float* __restrict__ lng, const float* __restrict__ lnb,
    float* __restrict__ xnew, unsigned short* __restrict__ h, int K)
{
    __shared__ __align__(16) char smem[73728];
    float (*vals)[264] = (float(*)[264])smem;
    const int t = threadIdx.x;
    const int r0 = blockIdx.x * 32;
    const int wid = t >> 6, lane = t & 63;
    const int lrow = lane & 15, lk8 = (lane >> 4) * 8;
    const int xsw = (lrow & 7) << 3;
    const int srcsw = ((lane & 7) ^ (lane >> 3)) << 3;

    auto stage = [&](int k0, int bsel) {
        unsigned short (*Ash)[64] = (unsigned short(*)[64])(smem + bsel * 4096);
        unsigned short (*Bsh)[64] = (unsigned short(*)[64])(smem + 8192 + bsel * 32768);
        if (wid < 4)
            GLOAD16(A + (size_t)(r0 + wid * 8 + (lane >> 3)) * K + k0 + srcsw, &Ash[wid * 8][0]);
        const unsigned short* gb = WT + (size_t)(wid * 32 + (lane >> 3)) * K + k0 + srcsw;
        unsigned short* lbp = &Bsh[wid * 32][0];
        #pragma unroll
        for (int i = 0; i < 4; i++)
            GLOAD16(gb + (size_t)(i * 8) * K, lbp + i * 8 * 64);
    };

    f32x4 acc[2][2] = {};
    stage(0, 0);
    int cur = 0;
    for (int k0 = 0; k0 < K; k0 += 64) {
        if (k0 + 64 < K) {
            stage(k0 + 64, cur ^ 1);
            if (wid < 4) asm volatile("s_waitcnt vmcnt(5)" ::: "memory");
            else         asm volatile("s_waitcnt vmcnt(4)" ::: "memory");
        } else {
            asm volatile("s_waitcnt vmcnt(0)" ::: "memory");
        }
        __builtin_amdgcn_s_barrier();
        __builtin_amdgcn_sched_barrier(0);
        unsigned short (*Ash)[64] = (unsigned short(*)[64])(smem + cur * 4096);
        unsigned short (*Bsh)[64] = (unsigned short(*)[64])(smem + 8192 + cur * 32768);
        #pragma unroll
        for (int ks = 0; ks < 2; ks++) {
            bf16x8 a0 = *(const bf16x8*)&Ash[lrow][(ks * 32 + lk8) ^ xsw];
            bf16x8 a1 = *(const bf16x8*)&Ash[16 + lrow][(ks * 32 + lk8) ^ xsw];
            #pragma unroll
            for (int nf = 0; nf < 2; nf++) {
                bf16x8 bfr = *(const bf16x8*)&Bsh[wid * 32 + nf * 16 + lrow][(ks * 32 + lk8) ^ xsw];
                acc[0][nf] = __builtin_amdgcn_mfma_f32_16x16x32_bf16(a0, bfr, acc[0][nf], 0, 0, 0);
                acc[1][nf] = __builtin_amdgcn_mfma_f32_16x16x32_bf16(a1, bfr, acc[1][nf], 0, 0, 0);
            }
        }
        __builtin_amdgcn_s_barrier();
        cur ^= 1;
    }
    __syncthreads();
    #pragma unroll
    for (int m = 0; m < 2; m++)
        #pragma unroll
        for (int nf = 0; nf < 2; nf++) {
            int col = wid * 32 + nf * 16 + lrow;
            float bv = bias[col];
            #pragma unroll
            for (int r = 0; r < 4; r++) {
                int row = m * 16 + (lane >> 4) * 4 + r;
                vals[row][col] = acc[m][nf][r] + bv + res[(size_t)(r0 + row) * 256 + col];
            }
        }
    __syncthreads();
    const int row = t >> 4, c4 = (t & 15) * 4;
    float s = 0.f, sq = 0.f;
    #pragma unroll
    for (int j = 0; j < 4; j++) {
        float4 v4 = *(const float4*)&vals[row][c4 + j * 64];
        s += v4.x + v4.y + v4.z + v4.w;
        sq += v4.x * v4.x + v4.y * v4.y + v4.z * v4.z + v4.w * v4.w;
    }
    s += __shfl_xor(s, 1); sq += __shfl_xor(sq, 1);
    s += __shfl_xor(s, 2); sq += __shfl_xor(sq, 2);
    s += __shfl_xor(s, 4); sq += __shfl_xor(sq, 4);
    s += __shfl_xor(s, 8); sq += __shfl_xor(sq, 8);
    float mean = s * (1.f / 256.f);
    float rs = rsqrtf(sq * (1.f / 256.f) - mean * mean + 1e-5f);
    const size_t gbase = (size_t)(r0 + row) * 256;
    #pragma unroll
    for (int j = 0; j < 4; j++) {
        int col = c4 + j * 64;
        float4 v4 = *(const float4*)&vals[row][col];
        *(float4*)(xnew + gbase + col) = v4;
        if (lng) {
            float4 g4 = *(const float4*)(lng + col);
            float4 b4 = *(const float4*)(lnb + col);
            ushort4 o;
            o.x = f2b((v4.x - mean) * rs * g4.x + b4.x);
            o.y = f2b((v4.y - mean) * rs * g4.y + b4.y);
            o.z = f2b((v4.z - mean) * rs * g4.z + b4.z);
            o.w = f2b((v4.w - mean) * rs * g4.w + b4.w);
            *(ushort4*)(h + gbase + col) = o;
        }
    }
}

// =============== GN2 ===============
__global__ __launch_bounds__(256) void k_gn2(
    const float* __restrict__ din, const float* __restrict__ g2, const float* __restrict__ be2,
    unsigned short* __restrict__ dout)
{
    const int t = threadIdx.x;
    const int w = t >> 6, lane = t & 63;
    const int p = blockIdx.x * 2 + (w >> 1), g = w & 1;
    float4 v = ((const float4*)(din + (size_t)p * 512 + g * 256))[lane];
    float s = v.x + v.y + v.z + v.w;
    float sq = v.x * v.x + v.y * v.y + v.z * v.z + v.w * v.w;
    #pragma unroll
    for (int m = 1; m < 64; m <<= 1) { s += __shfl_xor(s, m, 64); sq += __shfl_xor(sq, m, 64); }
    float mean = s * (1.f / 256.f);
    float rs = rsqrtf(sq * (1.f / 256.f) - mean * mean + 1e-5f);
    int oc = g * 32 + (lane >> 1);
    float gg = g2[oc], bb = be2[oc];
    ushort4 o;
    o.x = f2b((v.x - mean) * rs * gg + bb);
    o.y = f2b((v.y - mean) * rs * gg + bb);
    o.z = f2b((v.z - mean) * rs * gg + bb);
    o.w = f2b((v.w - mean) * rs * gg + bb);
    ((ushort4*)(dout + (size_t)p * 512 + g * 256))[lane] = o;
}

// ====== LN(u)+LN(pos) -> xb f32, and hb = LN_{l1[0]}(xb) bf16. Wave per row. ======
__global__ __launch_bounds__(256) void k_lnpos(
    const float* __restrict__ u, const float* __restrict__ pos,
    const float* __restrict__ lndg, const float* __restrict__ lndb,
    const float* __restrict__ lnpg, const float* __restrict__ lnpb,
    const float* __restrict__ l1g0, const float* __restrict__ l1b0,
    float* __restrict__ xb, unsigned short* __restrict__ hb)
{
    const int t = threadIdx.x;
    const int row = blockIdx.x * 4 + (t >> 6);
    const int lane = t & 63;
    float4 v = ((const float4*)(u + (size_t)row * 256))[lane];
    float4 w = ((const float4*)(pos + (size_t)(row & 511) * 256))[lane];
    float s = v.x + v.y + v.z + v.w;
    float sq = v.x * v.x + v.y * v.y + v.z * v.z + v.w * v.w;
    float sp = w.x + w.y + w.z + w.w;
    float qp = w.x * w.x + w.y * w.y + w.z * w.z + w.w * w.w;
    #pragma unroll
    for (int m = 1; m < 64; m <<= 1) {
        s += __shfl_xor(s, m, 64); sq += __shfl_xor(sq, m, 64);
        sp += __shfl_xor(sp, m, 64); qp += __shfl_xor(qp, m, 64);
    }
    float mu = s * (1.f / 256.f), ru = rsqrtf(sq * (1.f / 256.f) - mu * mu + 1e-5f);
    float mp = sp * (1.f / 256.f), rp = rsqrtf(qp * (1.f / 256.f) - mp * mp + 1e-5f);
    float4 ga = ((const float4*)lndg)[lane], ba = ((const float4*)lndb)[lane];
    float4 gp = ((const float4*)lnpg)[lane], bp = ((const float4*)lnpb)[lane];
    float4 o;
    o.x = (v.x - mu) * ru * ga.x + ba.x + (w.x - mp) * rp * gp.x + bp.x;
    o.y = (v.y - mu) * ru * ga.y + ba.y + (w.y - mp) * rp * gp.y + bp.y;
    o.z = (v.z - mu) * ru * ga.z + ba.z + (w.z - mp) * rp * gp.z + bp.z;
    o.w = (v.w - mu) * ru * ga.w + ba.w + (w.w - mp) * rp * gp.w + bp.w;
    ((float4*)(xb + (size_t)row * 256))[lane] = o;
    float s2 = o.x + o.y + o.z + o.w;
    float q2 = o.x * o.x + o.y * o.y + o.z * o.z + o.w * o.w;
    #pragma unroll
    for (int m = 1; m < 64; m <<= 1) { s2 += __shfl_xor(s2, m, 64); q2 += __shfl_xor(q2, m, 64); }
    float mu2 = s2 * (1.f / 256.f), r2 = rsqrtf(q2 * (1.f / 256.f) - mu2 * mu2 + 1e-5f);
    float4 g4 = ((const float4*)l1g0)[lane], b4 = ((const float4*)l1b0)[lane];
    ushort4 ho;
    ho.x = f2b((o.x - mu2) * r2 * g4.x + b4.x);
    ho.y = f2b((o.y - mu2) * r2 * g4.y + b4.y);
    ho.z = f2b((o.z - mu2) * r2 * g4.z + b4.z);
    ho.w = f2b((o.w - mu2) * r2 * g4.w + b4.w);
    ((ushort4*)(hb + (size_t)row * 256))[lane] = ho;
}

// ====== MFMA flash attention: qkv bf16 [8192][768] -> o bf16 [8192][256] ======
__global__ __launch_bounds__(256) void k_attn3(
    const unsigned short* __restrict__ qkv, unsigned short* __restrict__ og)
{
    __shared__ unsigned short Ks[64][36];
    __shared__ unsigned short Vt[32][72];
    __shared__ unsigned short Pt[4][16][72];
    const int t = threadIdx.x;
    const int bid = blockIdx.x;
    const int b = bid >> 6, hh = (bid >> 3) & 7, qt = bid & 7;
    const int wid = t >> 6, lane = t & 63;
    const int lr = lane & 15, lk8 = (lane >> 4) * 8;
    const int qrow = b * 512 + qt * 64 + wid * 16 + lr;
    const bf16x8 qf = *(const bf16x8*)(qkv + (size_t)qrow * 768 + hh * 32 + lk8);
    f32x4 O0 = {}, O1 = {};
    float mreg[4] = { -1e30f, -1e30f, -1e30f, -1e30f };
    float lreg[4] = {};
    const float scale = 0.17677669529663687f;
    for (int kv0 = 0; kv0 < 512; kv0 += 64) {
        __syncthreads();
        {
            int kvr = t >> 2, dd = (t & 3) * 8;
            size_t base = (size_t)(b * 512 + kv0 + kvr) * 768 + hh * 32;
            *(bf16x8*)&Ks[kvr][dd] = *(const bf16x8*)(qkv + base + 256 + dd);
            bf16x8 v8 = *(const bf16x8*)(qkv + base + 512 + dd);
            #pragma unroll
            for (int j = 0; j < 8; j++) Vt[dd + j][kvr] = (unsigned short)v8[j];
        }
        __syncthreads();
        f32x4 st[4];
        #pragma unroll
        for (int tt = 0; tt < 4; tt++) {
            bf16x8 kf = *(const bf16x8*)&Ks[tt * 16 + lr][lk8];
            st[tt] = __builtin_amdgcn_mfma_f32_16x16x32_bf16(qf, kf, (f32x4){}, 0, 0, 0);
        }
        float mnew[4], csc[4], psum[4];
        #pragma unroll
        for (int r = 0; r < 4; r++) {
            st[0][r] *= scale; st[1][r] *= scale; st[2][r] *= scale; st[3][r] *= scale;
            float mx = fmaxf(fmaxf(st[0][r], st[1][r]), fmaxf(st[2][r], st[3][r]));
            mx = fmaxf(mx, __shfl_xor(mx, 1));
            mx = fmaxf(mx, __shfl_xor(mx, 2));
            mx = fmaxf(mx, __shfl_xor(mx, 4));
            mx = fmaxf(mx, __shfl_xor(mx, 8));
            mnew[r] = fmaxf(mreg[r], mx);
            csc[r] = __expf(mreg[r] - mnew[r]);
            mreg[r] = mnew[r];
            psum[r] = 0.f;
        }
        #pragma unroll
        for (int tt = 0; tt < 4; tt++)
            #pragma unroll
            for (int r = 0; r < 4; r++) {
                float p = __expf(st[tt][r] - mnew[r]);
                st[tt][r] = p;
                psum[r] += p;
            }
        #pragma unroll
        for (int r = 0; r < 4; r++) {
            psum[r] += __shfl_xor(psum[r], 1);
            psum[r] += __shfl_xor(psum[r], 2);
            psum[r] += __shfl_xor(psum[r], 4);
            psum[r] += __shfl_xor(psum[r], 8);
            lreg[r] = lreg[r] * csc[r] + psum[r];
            O0[r] *= csc[r]; O1[r] *= csc[r];
        }
        #pragma unroll
        for (int tt = 0; tt < 4; tt++)
            #pragma unroll
            for (int r = 0; r < 4; r++)
                Pt[wid][(lane >> 4) * 4 + r][tt * 16 + lr] = f2b(st[tt][r]);
        #pragma unroll
        for (int half = 0; half < 2; half++) {
            bf16x8 pa  = *(const bf16x8*)&Pt[wid][lr][half * 32 + lk8];
            bf16x8 vlo = *(const bf16x8*)&Vt[lr][half * 32 + lk8];
            bf16x8 vhi = *(const bf16x8*)&Vt[16 + lr][half * 32 + lk8];
            O0 = __builtin_amdgcn_mfma_f32_16x16x32_bf16(pa, vlo, O0, 0, 0, 0);
            O1 = __builtin_amdgcn_mfma_f32_16x16x32_bf16(pa, vhi, O1, 0, 0, 0);
        }
    }
    #pragma unroll
    for (int r = 0; r < 4; r++) {
        float inv = 1.f / lreg[r];
        size_t orow = (size_t)(b * 512 + qt * 64 + wid * 16 + (lane >> 4) * 4 + r) * 256 + hh * 32;
        og[orow + lr] = f2b(O0[r] * inv);
        og[orow + 16 + lr] = f2b(O1[r] * inv);
    }
}

extern "C" void kernel_launch(void* const* d_in, const int* in_sizes, int n_in,
                              void* d_out, int out_size, void* d_ws, size_t ws_size,
                              hipStream_t stream)
{
    const float* img  = (const float*)d_in[0];
    const float* bfac = (const float*)d_in[1];
    const float* w0  = (const float*)d_in[2];  const float* b0c = (const float*)d_in[3];
    const float* g1  = (const float*)d_in[4];  const float* be1 = (const float*)d_in[5];
    const float* w1  = (const float*)d_in[6];  const float* b1c = (const float*)d_in[7];
    const float* g2  = (const float*)d_in[8];  const float* be2 = (const float*)d_in[9];
    const float* w2  = (const float*)d_in[10]; const float* b2c = (const float*)d_in[11];
    const float* g3  = (const float*)d_in[12]; const float* be3 = (const float*)d_in[13];
    const float* wu  = (const float*)d_in[14]; const float* bu  = (const float*)d_in[15];
    const float* pos = (const float*)d_in[16];
    const float* lndg = (const float*)d_in[17]; const float* lndb = (const float*)d_in[18];
    const float* lnpg = (const float*)d_in[19]; const float* lnpb = (const float*)d_in[20];
    const float* Wq = (const float*)d_in[21]; const float* bq = (const float*)d_in[22];
    const float* Wk = (const float*)d_in[23]; const float* bk = (const float*)d_in[24];
    const float* Wv = (const float*)d_in[25]; const float* bv = (const float*)d_in[26];
    const float* Wo = (const float*)d_in[27]; const float* bo = (const float*)d_in[28];
    const float* l1g = (const float*)d_in[29]; const float* l1b = (const float*)d_in[30];
    const float* l2g = (const float*)d_in[31]; const float* l2b = (const float*)d_in[32];
    const float* W1 = (const float*)d_in[33]; const float* bf1 = (const float*)d_in[34];
    const float* W2 = (const float*)d_in[35]; const float* bf2 = (const float*)d_in[36];

    float* ws = (float*)d_ws;
    unsigned short* d0b   = (unsigned short*)(ws);              // [8192][2048] bf16
    float*          d1raw = ws + 8388608;                       // [8192][512] f32
    unsigned short* d1b   = (unsigned short*)(ws + 12582912);   // [8192][512] bf16
    float*          xb    = ws + 14680064;                      // [8192][256] f32
    unsigned short* w1T   = (unsigned short*)(ws + 16777216);
    unsigned short* w2T   = (unsigned short*)(ws + 17301504);
    unsigned short* wuTb  = (unsigned short*)(ws + 17334272);
    unsigned short* WqkvT = (unsigned short*)(ws + 17350656);   // 8x768x256
    unsigned short* WoT   = (unsigned short*)(ws + 18137088);
    unsigned short* W1T   = (unsigned short*)(ws + 18399232);
    unsigned short* W2T   = (unsigned short*)(ws + 19447808);
    float*          b1x   = ws + 20496384;
    float*          bqkv  = ws + 20496896;
    // Phase C overlay (d0b dead after conv1 GEMM):
    unsigned short* d2b   = (unsigned short*)(ws + 1048576);    // [8192][128] bf16
    float*          ub    = ws + 1572864;                       // [8192][256] f32
    // Phase D overlay:
    unsigned short* hb    = (unsigned short*)(ws);              // [8192][256] bf16
    unsigned short* qkvb  = (unsigned short*)(ws + 1048576);    // [8192][768] bf16
    unsigned short* obb   = (unsigned short*)(ws + 4194304);    // [8192][256] bf16
    unsigned short* m1b   = (unsigned short*)(ws + 5242880);    // [8192][1024] bf16
    float* xout = (float*)d_out;

    // Weight prep: ONE launch
    k_prep_all<<<29058, 256, 0, stream>>>(w1, w2, wu, b1c, Wq, Wk, Wv, bq, bk, bv, Wo, W1, W2,
                                          w1T, w2T, wuTb, b1x, WqkvT, bqkv, WoT, W1T, W2T);

    // Encoder (128x128 tiles: NXB = N/128)
    k_blur_conv0<<<8192, 256, 0, stream>>>(img, bfac, w0, b0c, g1, be1, d0b);
    k_gemm_bf16<<<4 * 64, 256, 0, stream>>>(d0b, w1T, b1x, nullptr, d1raw, 4, 512, 2048, 2, 0);
    k_gn2<<<4096, 256, 0, stream>>>(d1raw, g2, be2, d1b);
    k_gemm_gn<<<256, 512, 0, stream>>>(d1b, w2T, b2c, g3, be3, d2b);
    k_gemm_bf16<<<2 * 64, 256, 0, stream>>>(d2b, wuTb, bu, nullptr, ub, 2, 256, 128, 0, 0);
    k_lnpos<<<2048, 256, 0, stream>>>(ub, pos, lndg, lndb, lnpg, lnpb, l1g, l1b, xb, hb);

    // Transformer: per layer {qkv, attn, Wo+res+LN(l2), W1(gelu), W2+res+LN(next l1)}
    for (int i = 0; i < 8; i++) {
        k_gemm_bf16<<<6 * 64, 256, 0, stream>>>(hb, WqkvT + (size_t)i * 196608, bqkv + i * 768, nullptr, qkvb, 6, 768, 256, 0, 1);
        k_attn3<<<1024, 256, 0, stream>>>(qkvb, obb);
        k_gemm_ln<<<256, 512, 0, stream>>>(obb, WoT + (size_t)i * 65536, bo + i * 256, xb,
                                           l2g + i * 256, l2b + i * 256, xb, hb, 256);
        k_gemm_bf16<<<8 * 64, 256, 0, stream>>>(hb, W1T + (size_t)i * 262144, bf1 + i * 1024, nullptr, m1b, 8, 1024, 256, 1, 1);
        if (i < 7) {
            k_gemm_ln<<<256, 512, 0, stream>>>(m1b, W2T + (size_t)i * 262144, bf2 + i * 256, xb,
                                               l1g + (i + 1) * 256, l1b + (i + 1) * 256, xb, hb, 1024);
        } else {
            k_gemm_ln<<<256, 512, 0, stream>>>(m1b, W2T + (size_t)i * 262144, bf2 + i * 256, xb,
                                               nullptr, nullptr, xout, nullptr, 1024);
        }
    }
}

// Round 19
// 768.563 us; speedup vs baseline: 1.0262x; 1.0262x over previous
//
#include <hip/hip_runtime.h>
#include <hip/hip_bf16.h>

#define PI2F 9.869604401089358f

typedef __attribute__((ext_vector_type(8))) short bf16x8;
typedef __attribute__((ext_vector_type(4))) float f32x4;

#define GLOAD16(g, l) __builtin_amdgcn_global_load_lds( \
    (const __attribute__((address_space(1))) void*)(g), \
    (__attribute__((address_space(3))) void*)(l), 16, 0, 0)

__device__ inline unsigned short f2b(float v) {
    union { float f; unsigned u; } x; x.f = v;
    unsigned r = x.u + 0x7fffu + ((x.u >> 16) & 1u);
    return (unsigned short)(r >> 16);
}

__device__ inline float gelu_tanh(float v) {
    float u = 0.7978845608028654f * (v + 0.044715f * v * v * v);
    float th = 1.f - 2.f / (1.f + __expf(2.f * u));
    return 0.5f * v * (1.f + th);
}

// =============== Kernel A: unfold + separable circular blur + MFMA conv0 + leaky + GN(G=4) =====
__global__ __launch_bounds__(256) void k_blur_conv0(
    const float* __restrict__ img, const float* __restrict__ bfac,
    const float* __restrict__ w0, const float* __restrict__ b0c,
    const float* __restrict__ g1, const float* __restrict__ be1,
    unsigned short* __restrict__ d0)
{
    __shared__ float pa[512], pb[512], hsm[8];
    __shared__ unsigned short pbb[512];
    __shared__ unsigned short w0b[32][72];
    __shared__ float d0s[64 * 33];
    __shared__ float2 gstat[4];
    const int t = threadIdx.x, blk = blockIdx.x;
    const int b = blk >> 9, rem = blk & 511;
    const int zh = rem >> 6, yh = (rem >> 3) & 7, xh = rem & 7;

    #pragma unroll
    for (int i = 0; i < 2; i++) {
        int v = t + 256 * i;
        int z = v >> 6, y = (v >> 3) & 7, x = v & 7;
        pa[v] = img[(((size_t)(b * 8 + zh) * 8 + z) * 64 + yh * 8 + y) * 64 + xh * 8 + x];
    }
    #pragma unroll
    for (int i = 0; i < 8; i++) {
        int idx = i * 256 + t;
        w0b[idx >> 6][idx & 63] = f2b(w0[idx]);
    }
    if (t < 8) {
        float bf = bfac[blk];
        float c = bf * PI2F * (1.0f / 16.0f);
        float gk1 = __expf(-c), gk2 = __expf(-4.f * c), gk3 = __expf(-9.f * c), gk4 = __expf(-16.f * c);
        float d = (float)t;
        float h = 1.f + 2.f * (gk1 * cosf(0.7853981633974483f * d)
                             + gk2 * cosf(1.5707963267948966f * d)
                             + gk3 * cosf(2.356194490192345f * d))
                      + gk4 * cosf(3.141592653589793f * d);
        hsm[t] = 0.125f * h;
    }
    __syncthreads();
    #pragma unroll
    for (int i = 0; i < 2; i++) {
        int v = t + 256 * i; int x = v & 7; int base = v & ~7;
        float s = 0.f;
        #pragma unroll
        for (int m = 0; m < 8; m++) s += hsm[(x - m) & 7] * pa[base + m];
        pb[v] = s;
    }
    __syncthreads();
    #pragma unroll
    for (int i = 0; i < 2; i++) {
        int v = t + 256 * i; int y = (v >> 3) & 7; int base = (v & ~63) | (v & 7);
        float s = 0.f;
        #pragma unroll
        for (int m = 0; m < 8; m++) s += hsm[(y - m) & 7] * pb[base + m * 8];
        pa[v] = s;
    }
    __syncthreads();
    #pragma unroll
    for (int i = 0; i < 2; i++) {
        int v = t + 256 * i; int z = v >> 6; int base = v & 63;
        float s = 0.f;
        #pragma unroll
        for (int m = 0; m < 8; m++) s += hsm[(z - m) & 7] * pa[base + m * 64];
        pb[v] = s;
        pbb[v] = f2b(s);
    }
    __syncthreads();
    const int wid = t >> 6, lane = t & 63;
    const int lr = lane & 15, lk8 = (lane >> 4) * 8;
    {
        const int vox = wid * 16 + lr;
        const int szb = 2 * (vox >> 4) - 1, syb = 2 * ((vox >> 2) & 3) - 1, sxb = 2 * (vox & 3) - 1;
        f32x4 acc0 = {}, acc1 = {};
        #pragma unroll
        for (int ks = 0; ks < 2; ks++) {
            bf16x8 a;
            #pragma unroll
            for (int j = 0; j < 8; j++) {
                int tap = ks * 32 + lk8 + j;
                int sz = szb + (tap >> 4), sy = syb + ((tap >> 2) & 3), sx = sxb + (tap & 3);
                bool ok = (unsigned)sz < 8u && (unsigned)sy < 8u && (unsigned)sx < 8u;
                a[j] = ok ? (short)pbb[sz * 64 + sy * 8 + sx] : (short)0;
            }
            bf16x8 b0 = *(const bf16x8*)&w0b[lr][ks * 32 + lk8];
            bf16x8 b1 = *(const bf16x8*)&w0b[16 + lr][ks * 32 + lk8];
            acc0 = __builtin_amdgcn_mfma_f32_16x16x32_bf16(a, b0, acc0, 0, 0, 0);
            acc1 = __builtin_amdgcn_mfma_f32_16x16x32_bf16(a, b1, acc1, 0, 0, 0);
        }
        const float bA = b0c[lr], bB = b0c[16 + lr];
        #pragma unroll
        for (int r = 0; r < 4; r++) {
            int crow = wid * 16 + (lane >> 4) * 4 + r;
            float v0 = acc0[r] + bA; v0 = v0 >= 0.f ? v0 : 0.2f * v0;
            float v1 = acc1[r] + bB; v1 = v1 >= 0.f ? v1 : 0.2f * v1;
            d0s[crow * 33 + lr] = v0;
            d0s[crow * 33 + 16 + lr] = v1;
        }
    }
    __syncthreads();
    {
        int g = wid;
        float s = 0.f, sq = 0.f;
        #pragma unroll
        for (int cc = 0; cc < 8; cc++) { float v = d0s[lane * 33 + g * 8 + cc]; s += v; sq += v * v; }
        #pragma unroll
        for (int m = 1; m < 64; m <<= 1) { s += __shfl_xor(s, m, 64); sq += __shfl_xor(sq, m, 64); }
        if (lane == 0) {
            float mean = s * (1.f / 512.f);
            float var = sq * (1.f / 512.f) - mean * mean;
            gstat[g] = make_float2(mean, rsqrtf(var + 1e-5f));
        }
    }
    __syncthreads();
    size_t obase = (size_t)blk * 2048;
    #pragma unroll
    for (int i = 0; i < 8; i++) {
        int oi = t + 256 * i;
        int c = oi >> 6, vox = oi & 63;
        float2 st = gstat[oi >> 9];
        d0[obase + oi] = f2b((d0s[vox * 33 + c] - st.x) * st.y * g1[c] + be1[c]);
    }
}

// =============== ONE merged weight-prep kernel ===============
__global__ __launch_bounds__(256) void k_prep_all(
    const float* __restrict__ w1, const float* __restrict__ w2, const float* __restrict__ wu,
    const float* __restrict__ b1c,
    const float* __restrict__ Wq, const float* __restrict__ Wk, const float* __restrict__ Wv,
    const float* __restrict__ bq, const float* __restrict__ bk, const float* __restrict__ bv,
    const float* __restrict__ Wo, const float* __restrict__ W1, const float* __restrict__ W2,
    unsigned short* __restrict__ w1T, unsigned short* __restrict__ w2T,
    unsigned short* __restrict__ wuT, float* __restrict__ b1x,
    unsigned short* __restrict__ WqkvT, float* __restrict__ bqkv,
    unsigned short* __restrict__ WoT, unsigned short* __restrict__ W1T, unsigned short* __restrict__ W2T)
{
    const int blk = blockIdx.x, t = threadIdx.x;
    if (blk < 4096) {
        int idx = blk * 256 + t;
        int n = idx >> 11, k = idx & 2047;
        int oc = n >> 3, vox = n & 7;
        int oz = vox >> 2, oy = (vox >> 1) & 1, ox = vox & 1;
        int ci = k >> 6, sp = k & 63;
        int sz = sp >> 4, sy = (sp >> 2) & 3, sx = sp & 3;
        int kz = sz + 1 - 2 * oz, ky = sy + 1 - 2 * oy, kx = sx + 1 - 2 * ox;
        float v = 0.f;
        if ((unsigned)kz < 4u && (unsigned)ky < 4u && (unsigned)kx < 4u)
            v = w1[(size_t)oc * 2048 + ci * 64 + kz * 16 + ky * 4 + kx];
        w1T[idx] = f2b(v);
    } else if (blk < 4352) {
        int idx = (blk - 4096) * 256 + t;
        int n = idx >> 9, k = idx & 511;
        int ci = k >> 3, v = k & 7;
        int z = v >> 2, y = (v >> 1) & 1, x = v & 1;
        w2T[idx] = f2b(w2[(size_t)n * 4096 + ci * 64 + (z + 1) * 16 + (y + 1) * 4 + (x + 1)]);
    } else if (blk < 4480) {
        int idx = (blk - 4352) * 256 + t;
        wuT[idx] = f2b(wu[idx]);
    } else if (blk < 4482) {
        int idx = (blk - 4480) * 256 + t;
        b1x[idx] = b1c[idx >> 3];
    } else if (blk < 10626) {
        int task = blk - 4482;
        int l = task / 768, n = task % 768;
        int sel = n >> 8, col = n & 255;
        const float* W = sel == 0 ? Wq : sel == 1 ? Wk : Wv;
        const float* bb = sel == 0 ? bq : sel == 1 ? bk : bv;
        WqkvT[((size_t)l * 768 + n) * 256 + t] = f2b(W[(size_t)l * 65536 + (size_t)t * 256 + col]);
        if (t == 0) bqkv[l * 768 + n] = bb[l * 256 + col];
    } else if (blk < 12674) {
        int gid = (blk - 10626) * 256 + t;
        int l = gid >> 16, w = gid & 65535;
        int n = w >> 8, k = w & 255;
        WoT[gid] = f2b(Wo[(size_t)l * 65536 + (size_t)k * 256 + n]);
    } else if (blk < 20866) {
        int gid = (blk - 12674) * 256 + t;
        int l = gid >> 18, w = gid & 262143;
        int n = w >> 8, k = w & 255;
        W1T[gid] = f2b(W1[(size_t)l * 262144 + (size_t)k * 1024 + n]);
    } else {
        int gid = (blk - 20866) * 256 + t;
        int l = gid >> 18, w = gid & 262143;
        int n = w >> 10, k = w & 1023;
        W2T[gid] = f2b(W2[(size_t)l * 262144 + (size_t)k * 256 + n]);
    }
}

// ====== MFMA GEMM: XCD swizzle + gload_lds + T2 swizzle + dbuf with COUNTED vmcnt (T4) ======
template<int BM>
__global__ __launch_bounds__(256) void k_gemm_bf16(
    const unsigned short* __restrict__ A, const unsigned short* __restrict__ WT,
    const float* __restrict__ bias, const float* __restrict__ res,
    void* __restrict__ Cout, int NXB, int N, int K, int act, int obf)
{
    constexpr int MREP = BM / 32;
    __shared__ unsigned short Ash[2][BM][64];
    __shared__ unsigned short Bsh[2][64][64];
    const int t = threadIdx.x;
    const int lb = blockIdx.x;
    const int xcd = lb & 7, j = lb >> 3;
    const int gy = xcd * 8 + j / NXB, gx = j % NXB;
    const int c0 = gx * 64;
    const int r0 = gy * BM;
    const int wid = t >> 6, lane = t & 63;
    const int wr = wid >> 1, wc = wid & 1;
    const int lrow = lane & 15, lk = (lane >> 4) * 8;
    const int xsw = (lrow & 7) << 3;
    const int srcsw = ((lane & 7) ^ (lane >> 3)) << 3;

    auto stage = [&](int k0, int bsel) {
        const unsigned short* ga = A + (size_t)(r0 + wid * (BM / 4) + (lane >> 3)) * K + k0 + srcsw;
        unsigned short* la = &Ash[bsel][wid * (BM / 4)][0];
        #pragma unroll
        for (int i = 0; i < BM / 32; i++)
            GLOAD16(ga + (size_t)(i * 8) * K, la + i * 8 * 64);
        const unsigned short* gb = WT + (size_t)(c0 + wid * 16 + (lane >> 3)) * K + k0 + srcsw;
        unsigned short* lbp = &Bsh[bsel][wid * 16][0];
        #pragma unroll
        for (int i = 0; i < 2; i++)
            GLOAD16(gb + (size_t)(i * 8) * K, lbp + i * 8 * 64);
    };

    f32x4 acc[MREP][2] = {};
    stage(0, 0);
    int cur = 0;
    for (int k0 = 0; k0 < K; k0 += 64) {
        if (k0 + 64 < K) {
            stage(k0 + 64, cur ^ 1);
            static_assert(BM == 128, "vmcnt literal assumes BM=128 (6 loads/wave/stage)");
            asm volatile("s_waitcnt vmcnt(6)" ::: "memory");
        } else {
            asm volatile("s_waitcnt vmcnt(0)" ::: "memory");
        }
        __builtin_amdgcn_s_barrier();
        __builtin_amdgcn_sched_barrier(0);
        #pragma unroll
        for (int ks = 0; ks < 2; ks++) {
            bf16x8 b0 = *(const bf16x8*)&Bsh[cur][wc * 32 + lrow][(ks * 32 + lk) ^ xsw];
            bf16x8 b1 = *(const bf16x8*)&Bsh[cur][wc * 32 + 16 + lrow][(ks * 32 + lk) ^ xsw];
            #pragma unroll
            for (int m = 0; m < MREP; m++) {
                bf16x8 a = *(const bf16x8*)&Ash[cur][wr * (BM / 2) + m * 16 + lrow][(ks * 32 + lk) ^ xsw];
                acc[m][0] = __builtin_amdgcn_mfma_f32_16x16x32_bf16(a, b0, acc[m][0], 0, 0, 0);
                acc[m][1] = __builtin_amdgcn_mfma_f32_16x16x32_bf16(a, b1, acc[m][1], 0, 0, 0);
            }
        }
        __builtin_amdgcn_s_barrier();
        cur ^= 1;
    }
    const int rbase = r0 + wr * (BM / 2) + (lane >> 4) * 4;
    #pragma unroll
    for (int n = 0; n < 2; n++) {
        const int col = c0 + wc * 32 + n * 16 + lrow;
        const float bv = bias[col];
        #pragma unroll
        for (int m = 0; m < MREP; m++) {
            #pragma unroll
            for (int r = 0; r < 4; r++) {
                float v = acc[m][n][r] + bv;
                if (act == 1) v = gelu_tanh(v);
                else if (act == 2) v = v >= 0.f ? v : 0.2f * v;
                size_t off = (size_t)(rbase + m * 16 + r) * N + col;
                if (res) v += res[off];
                if (obf) ((unsigned short*)Cout)[off] = f2b(v);
                else ((float*)Cout)[off] = v;
            }
        }
    }
}

// ====== Fused conv2 GEMM + leaky + row-GN(128) -> bf16 ======
__global__ __launch_bounds__(512) void k_gemm_gn(
    const unsigned short* __restrict__ A, const unsigned short* __restrict__ WT,
    const float* __restrict__ bias, const float* __restrict__ g3, const float* __restrict__ be3,
    unsigned short* __restrict__ out)
{
    __shared__ __align__(16) char smem[23040];
    unsigned short (*Ash)[72] = (unsigned short(*)[72])smem;
    unsigned short (*Bsh)[72] = (unsigned short(*)[72])(smem + 4608);
    float (*vals)[136] = (float(*)[136])smem;
    const int t = threadIdx.x;
    const int r0 = blockIdx.x * 32;
    const int wid = t >> 6, lane = t & 63;
    const int mrow = wid >> 2, colq = wid & 3;
    const int lr = lane & 15, lk8 = (lane >> 4) * 8;
    f32x4 acc[2] = {};
    for (int k0 = 0; k0 < 512; k0 += 64) {
        __syncthreads();
        if (t < 256) {
            int f = t * 8;
            int r = f >> 6, kk = f & 63;
            *(bf16x8*)&Ash[r][kk] = *(const bf16x8*)(A + (size_t)(r0 + r) * 512 + k0 + kk);
        }
        #pragma unroll
        for (int i = 0; i < 2; i++) {
            int f = (i * 512 + t) * 8;
            int r = f >> 6, kk = f & 63;
            *(bf16x8*)&Bsh[r][kk] = *(const bf16x8*)(WT + (size_t)r * 512 + k0 + kk);
        }
        __syncthreads();
        #pragma unroll
        for (int ks = 0; ks < 2; ks++) {
            bf16x8 a = *(const bf16x8*)&Ash[mrow * 16 + lr][ks * 32 + lk8];
            #pragma unroll
            for (int nf = 0; nf < 2; nf++) {
                bf16x8 bb = *(const bf16x8*)&Bsh[colq * 32 + nf * 16 + lr][ks * 32 + lk8];
                acc[nf] = __builtin_amdgcn_mfma_f32_16x16x32_bf16(a, bb, acc[nf], 0, 0, 0);
            }
        }
    }
    __syncthreads();
    #pragma unroll
    for (int nf = 0; nf < 2; nf++) {
        int col = colq * 32 + nf * 16 + lr;
        float bv = bias[col];
        #pragma unroll
        for (int r = 0; r < 4; r++) {
            int row = mrow * 16 + (lane >> 4) * 4 + r;
            float v = acc[nf][r] + bv;
            vals[row][col] = v >= 0.f ? v : 0.2f * v;
        }
    }
    __syncthreads();
    const int row = t >> 4, cc0 = (t & 15) * 8;
    float s = 0.f, sq = 0.f;
    #pragma unroll
    for (int j = 0; j < 8; j++) {
        float v = vals[row][cc0 + j];
        s += v; sq += v * v;
    }
    s += __shfl_xor(s, 1); sq += __shfl_xor(sq, 1);
    s += __shfl_xor(s, 2); sq += __shfl_xor(sq, 2);
    s += __shfl_xor(s, 4); sq += __shfl_xor(sq, 4);
    s += __shfl_xor(s, 8); sq += __shfl_xor(sq, 8);
    float mean = s * (1.f / 128.f);
    float rs = rsqrtf(sq * (1.f / 128.f) - mean * mean + 1e-5f);
    ushort4 o[2];
    #pragma unroll
    for (int h = 0; h < 2; h++) {
        #pragma unroll
        for (int j = 0; j < 4; j++) {
            int col = cc0 + h * 4 + j;
            float v = (vals[row][col] - mean) * rs * g3[col] + be3[col];
            ((unsigned short*)&o[h])[j] = f2b(v);
        }
    }
    *(ushort4*)(out + (size_t)(r0 + row) * 128 + cc0) = o[0];
    *(ushort4*)(out + (size_t)(r0 + row) * 128 + cc0 + 4) = o[1];
}

// ====== Fused GEMM + residual + row-LN (Wo and W2), dbuf + counted vmcnt ======
__global__ __launch_bounds__(512) void k_gemm_ln(
    const unsigned short* __restrict__ A, const unsigned short* __restrict__ WT,
    const float* __restrict__ bias, const float* __restrict__ res,
    const float* __restrict__ lng, const float* __restrict__ lnb,
    float* __restrict__ xnew, unsigned short* __restrict__ h, int K)
{
    __shared__ __align__(16) char smem[73728];
    float (*vals)[264] = (float(*)[264])smem;
    const int t = threadIdx.x;
    const int r0 = blockIdx.x * 32;
    const int wid = t >> 6, lane = t & 63;
    const int lrow = lane & 15, lk8 = (lane >> 4) * 8;
    const int xsw = (lrow & 7) << 3;
    const int srcsw = ((lane & 7) ^ (lane >> 3)) << 3;

    auto stage = [&](int k0, int bsel) {
        unsigned short (*Ash)[64] = (unsigned short(*)[64])(smem + bsel * 4096);
        unsigned short (*Bsh)[64] = (unsigned short(*)[64])(smem + 8192 + bsel * 32768);
        if (wid < 4)
            GLOAD16(A + (size_t)(r0 + wid * 8 + (lane >> 3)) * K + k0 + srcsw, &Ash[wid * 8][0]);
        const unsigned short* gb = WT + (size_t)(wid * 32 + (lane >> 3)) * K + k0 + srcsw;
        unsigned short* lbp = &Bsh[wid * 32][0];
        #pragma unroll
        for (int i = 0; i < 4; i++)
            GLOAD16(gb + (size_t)(i * 8) * K, lbp + i * 8 * 64);
    };

    f32x4 acc[2][2] = {};
    stage(0, 0);
    int cur = 0;
    for (int k0 = 0; k0 < K; k0 += 64) {
        if (k0 + 64 < K) {
            stage(k0 + 64, cur ^ 1);
            if (wid < 4) asm volatile("s_waitcnt vmcnt(5)" ::: "memory");
            else         asm volatile("s_waitcnt vmcnt(4)" ::: "memory");
        } else {
            asm volatile("s_waitcnt vmcnt(0)" ::: "memory");
        }
        __builtin_amdgcn_s_barrier();
        __builtin_amdgcn_sched_barrier(0);
        unsigned short (*Ash)[64] = (unsigned short(*)[64])(smem + cur * 4096);
        unsigned short (*Bsh)[64] = (unsigned short(*)[64])(smem + 8192 + cur * 32768);
        #pragma unroll
        for (int ks = 0; ks < 2; ks++) {
            bf16x8 a0 = *(const bf16x8*)&Ash[lrow][(ks * 32 + lk8) ^ xsw];
            bf16x8 a1 = *(const bf16x8*)&Ash[16 + lrow][(ks * 32 + lk8) ^ xsw];
            #pragma unroll
            for (int nf = 0; nf < 2; nf++) {
                bf16x8 bfr = *(const bf16x8*)&Bsh[wid * 32 + nf * 16 + lrow][(ks * 32 + lk8) ^ xsw];
                acc[0][nf] = __builtin_amdgcn_mfma_f32_16x16x32_bf16(a0, bfr, acc[0][nf], 0, 0, 0);
                acc[1][nf] = __builtin_amdgcn_mfma_f32_16x16x32_bf16(a1, bfr, acc[1][nf], 0, 0, 0);
            }
        }
        __builtin_amdgcn_s_barrier();
        cur ^= 1;
    }
    __syncthreads();
    #pragma unroll
    for (int m = 0; m < 2; m++)
        #pragma unroll
        for (int nf = 0; nf < 2; nf++) {
            int col = wid * 32 + nf * 16 + lrow;
            float bv = bias[col];
            #pragma unroll
            for (int r = 0; r < 4; r++) {
                int row = m * 16 + (lane >> 4) * 4 + r;
                vals[row][col] = acc[m][nf][r] + bv + res[(size_t)(r0 + row) * 256 + col];
            }
        }
    __syncthreads();
    const int row = t >> 4, c4 = (t & 15) * 4;
    float s = 0.f, sq = 0.f;
    #pragma unroll
    for (int j = 0; j < 4; j++) {
        float4 v4 = *(const float4*)&vals[row][c4 + j * 64];
        s += v4.x + v4.y + v4.z + v4.w;
        sq += v4.x * v4.x + v4.y * v4.y + v4.z * v4.z + v4.w * v4.w;
    }
    s += __shfl_xor(s, 1); sq += __shfl_xor(sq, 1);
    s += __shfl_xor(s, 2); sq += __shfl_xor(sq, 2);
    s += __shfl_xor(s, 4); sq += __shfl_xor(sq, 4);
    s += __shfl_xor(s, 8); sq += __shfl_xor(sq, 8);
    float mean = s * (1.f / 256.f);
    float rs = rsqrtf(sq * (1.f / 256.f) - mean * mean + 1e-5f);
    const size_t gbase = (size_t)(r0 + row) * 256;
    #pragma unroll
    for (int j = 0; j < 4; j++) {
        int col = c4 + j * 64;
        float4 v4 = *(const float4*)&vals[row][col];
        *(float4*)(xnew + gbase + col) = v4;
        if (lng) {
            float4 g4 = *(const float4*)(lng + col);
            float4 b4 = *(const float4*)(lnb + col);
            ushort4 o;
            o.x = f2b((v4.x - mean) * rs * g4.x + b4.x);
            o.y = f2b((v4.y - mean) * rs * g4.y + b4.y);
            o.z = f2b((v4.z - mean) * rs * g4.z + b4.z);
            o.w = f2b((v4.w - mean) * rs * g4.w + b4.w);
            *(ushort4*)(h + gbase + col) = o;
        }
    }
}

// =============== GN2 ===============
__global__ __launch_bounds__(256) void k_gn2(
    const float* __restrict__ din, const float* __restrict__ g2, const float* __restrict__ be2,
    unsigned short* __restrict__ dout)
{
    const int t = threadIdx.x;
    const int w = t >> 6, lane = t & 63;
    const int p = blockIdx.x * 2 + (w >> 1), g = w & 1;
    float4 v = ((const float4*)(din + (size_t)p * 512 + g * 256))[lane];
    float s = v.x + v.y + v.z + v.w;
    float sq = v.x * v.x + v.y * v.y + v.z * v.z + v.w * v.w;
    #pragma unroll
    for (int m = 1; m < 64; m <<= 1) { s += __shfl_xor(s, m, 64); sq += __shfl_xor(sq, m, 64); }
    float mean = s * (1.f / 256.f);
    float rs = rsqrtf(sq * (1.f / 256.f) - mean * mean + 1e-5f);
    int oc = g * 32 + (lane >> 1);
    float gg = g2[oc], bb = be2[oc];
    ushort4 o;
    o.x = f2b((v.x - mean) * rs * gg + bb);
    o.y = f2b((v.y - mean) * rs * gg + bb);
    o.z = f2b((v.z - mean) * rs * gg + bb);
    o.w = f2b((v.w - mean) * rs * gg + bb);
    ((ushort4*)(dout + (size_t)p * 512 + g * 256))[lane] = o;
}

// ====== LN(u)+LN(pos) -> xb f32, and hb = LN_{l1[0]}(xb) bf16. Wave per row. ======
__global__ __launch_bounds__(256) void k_lnpos(
    const float* __restrict__ u, const float* __restrict__ pos,
    const float* __restrict__ lndg, const float* __restrict__ lndb,
    const float* __restrict__ lnpg, const float* __restrict__ lnpb,
    const float* __restrict__ l1g0, const float* __restrict__ l1b0,
    float* __restrict__ xb, unsigned short* __restrict__ hb)
{
    const int t = threadIdx.x;
    const int row = blockIdx.x * 4 + (t >> 6);
    const int lane = t & 63;
    float4 v = ((const float4*)(u + (size_t)row * 256))[lane];
    float4 w = ((const float4*)(pos + (size_t)(row & 511) * 256))[lane];
    float s = v.x + v.y + v.z + v.w;
    float sq = v.x * v.x + v.y * v.y + v.z * v.z + v.w * v.w;
    float sp = w.x + w.y + w.z + w.w;
    float qp = w.x * w.x + w.y * w.y + w.z * w.z + w.w * w.w;
    #pragma unroll
    for (int m = 1; m < 64; m <<= 1) {
        s += __shfl_xor(s, m, 64); sq += __shfl_xor(sq, m, 64);
        sp += __shfl_xor(sp, m, 64); qp += __shfl_xor(qp, m, 64);
    }
    float mu = s * (1.f / 256.f), ru = rsqrtf(sq * (1.f / 256.f) - mu * mu + 1e-5f);
    float mp = sp * (1.f / 256.f), rp = rsqrtf(qp * (1.f / 256.f) - mp * mp + 1e-5f);
    float4 ga = ((const float4*)lndg)[lane], ba = ((const float4*)lndb)[lane];
    float4 gp = ((const float4*)lnpg)[lane], bp = ((const float4*)lnpb)[lane];
    float4 o;
    o.x = (v.x - mu) * ru * ga.x + ba.x + (w.x - mp) * rp * gp.x + bp.x;
    o.y = (v.y - mu) * ru * ga.y + ba.y + (w.y - mp) * rp * gp.y + bp.y;
    o.z = (v.z - mu) * ru * ga.z + ba.z + (w.z - mp) * rp * gp.z + bp.z;
    o.w = (v.w - mu) * ru * ga.w + ba.w + (w.w - mp) * rp * gp.w + bp.w;
    ((float4*)(xb + (size_t)row * 256))[lane] = o;
    float s2 = o.x + o.y + o.z + o.w;
    float q2 = o.x * o.x + o.y * o.y + o.z * o.z + o.w * o.w;
    #pragma unroll
    for (int m = 1; m < 64; m <<= 1) { s2 += __shfl_xor(s2, m, 64); q2 += __shfl_xor(q2, m, 64); }
    float mu2 = s2 * (1.f / 256.f), r2 = rsqrtf(q2 * (1.f / 256.f) - mu2 * mu2 + 1e-5f);
    float4 g4 = ((const float4*)l1g0)[lane], b4 = ((const float4*)l1b0)[lane];
    ushort4 ho;
    ho.x = f2b((o.x - mu2) * r2 * g4.x + b4.x);
    ho.y = f2b((o.y - mu2) * r2 * g4.y + b4.y);
    ho.z = f2b((o.z - mu2) * r2 * g4.z + b4.z);
    ho.w = f2b((o.w - mu2) * r2 * g4.w + b4.w);
    ((ushort4*)(hb + (size_t)row * 256))[lane] = ho;
}

// ====== MFMA flash attention: qkv bf16 [8192][768] -> o bf16 [8192][256] ======
__global__ __launch_bounds__(256) void k_attn3(
    const unsigned short* __restrict__ qkv, unsigned short* __restrict__ og)
{
    __shared__ unsigned short Ks[64][36];
    __shared__ unsigned short Vt[32][72];
    __shared__ unsigned short Pt[4][16][72];
    const int t = threadIdx.x;
    const int bid = blockIdx.x;
    const int b = bid >> 6, hh = (bid >> 3) & 7, qt = bid & 7;
    const int wid = t >> 6, lane = t & 63;
    const int lr = lane & 15, lk8 = (lane >> 4) * 8;
    const int qrow = b * 512 + qt * 64 + wid * 16 + lr;
    const bf16x8 qf = *(const bf16x8*)(qkv + (size_t)qrow * 768 + hh * 32 + lk8);
    f32x4 O0 = {}, O1 = {};
    float mreg[4] = { -1e30f, -1e30f, -1e30f, -1e30f };
    float lreg[4] = {};
    const float scale = 0.17677669529663687f;
    for (int kv0 = 0; kv0 < 512; kv0 += 64) {
        __syncthreads();
        {
            int kvr = t >> 2, dd = (t & 3) * 8;
            size_t base = (size_t)(b * 512 + kv0 + kvr) * 768 + hh * 32;
            *(bf16x8*)&Ks[kvr][dd] = *(const bf16x8*)(qkv + base + 256 + dd);
            bf16x8 v8 = *(const bf16x8*)(qkv + base + 512 + dd);
            #pragma unroll
            for (int j = 0; j < 8; j++) Vt[dd + j][kvr] = (unsigned short)v8[j];
        }
        __syncthreads();
        f32x4 st[4];
        #pragma unroll
        for (int tt = 0; tt < 4; tt++) {
            bf16x8 kf = *(const bf16x8*)&Ks[tt * 16 + lr][lk8];
            st[tt] = __builtin_amdgcn_mfma_f32_16x16x32_bf16(qf, kf, (f32x4){}, 0, 0, 0);
        }
        float mnew[4], csc[4], psum[4];
        #pragma unroll
        for (int r = 0; r < 4; r++) {
            st[0][r] *= scale; st[1][r] *= scale; st[2][r] *= scale; st[3][r] *= scale;
            float mx = fmaxf(fmaxf(st[0][r], st[1][r]), fmaxf(st[2][r], st[3][r]));
            mx = fmaxf(mx, __shfl_xor(mx, 1));
            mx = fmaxf(mx, __shfl_xor(mx, 2));
            mx = fmaxf(mx, __shfl_xor(mx, 4));
            mx = fmaxf(mx, __shfl_xor(mx, 8));
            mnew[r] = fmaxf(mreg[r], mx);
            csc[r] = __expf(mreg[r] - mnew[r]);
            mreg[r] = mnew[r];
            psum[r] = 0.f;
        }
        #pragma unroll
        for (int tt = 0; tt < 4; tt++)
            #pragma unroll
            for (int r = 0; r < 4; r++) {
                float p = __expf(st[tt][r] - mnew[r]);
                st[tt][r] = p;
                psum[r] += p;
            }
        #pragma unroll
        for (int r = 0; r < 4; r++) {
            psum[r] += __shfl_xor(psum[r], 1);
            psum[r] += __shfl_xor(psum[r], 2);
            psum[r] += __shfl_xor(psum[r], 4);
            psum[r] += __shfl_xor(psum[r], 8);
            lreg[r] = lreg[r] * csc[r] + psum[r];
            O0[r] *= csc[r]; O1[r] *= csc[r];
        }
        #pragma unroll
        for (int tt = 0; tt < 4; tt++)
            #pragma unroll
            for (int r = 0; r < 4; r++)
                Pt[wid][(lane >> 4) * 4 + r][tt * 16 + lr] = f2b(st[tt][r]);
        #pragma unroll
        for (int half = 0; half < 2; half++) {
            bf16x8 pa  = *(const bf16x8*)&Pt[wid][lr][half * 32 + lk8];
            bf16x8 vlo = *(const bf16x8*)&Vt[lr][half * 32 + lk8];
            bf16x8 vhi = *(const bf16x8*)&Vt[16 + lr][half * 32 + lk8];
            O0 = __builtin_amdgcn_mfma_f32_16x16x32_bf16(pa, vlo, O0, 0, 0, 0);
            O1 = __builtin_amdgcn_mfma_f32_16x16x32_bf16(pa, vhi, O1, 0, 0, 0);
        }
    }
    #pragma unroll
    for (int r = 0; r < 4; r++) {
        float inv = 1.f / lreg[r];
        size_t orow = (size_t)(b * 512 + qt * 64 + wid * 16 + (lane >> 4) * 4 + r) * 256 + hh * 32;
        og[orow + lr] = f2b(O0[r] * inv);
        og[orow + 16 + lr] = f2b(O1[r] * inv);
    }
}

extern "C" void kernel_launch(void* const* d_in, const int* in_sizes, int n_in,
                              void* d_out, int out_size, void* d_ws, size_t ws_size,
                              hipStream_t stream)
{
    const float* img  = (const float*)d_in[0];
    const float* bfac = (const float*)d_in[1];
    const float* w0  = (const float*)d_in[2];  const float* b0c = (const float*)d_in[3];
    const float* g1  = (const float*)d_in[4];  const float* be1 = (const float*)d_in[5];
    const float* w1  = (const float*)d_in[6];  const float* b1c = (const float*)d_in[7];
    const float* g2  = (const float*)d_in[8];  const float* be2 = (const float*)d_in[9];
    const float* w2  = (const float*)d_in[10]; const float* b2c = (const float*)d_in[11];
    const float* g3  = (const float*)d_in[12]; const float* be3 = (const float*)d_in[13];
    const float* wu  = (const float*)d_in[14]; const float* bu  = (const float*)d_in[15];
    const float* pos = (const float*)d_in[16];
    const float* lndg = (const float*)d_in[17]; const float* lndb = (const float*)d_in[18];
    const float* lnpg = (const float*)d_in[19]; const float* lnpb = (const float*)d_in[20];
    const float* Wq = (const float*)d_in[21]; const float* bq = (const float*)d_in[22];
    const float* Wk = (const float*)d_in[23]; const float* bk = (const float*)d_in[24];
    const float* Wv = (const float*)d_in[25]; const float* bv = (const float*)d_in[26];
    const float* Wo = (const float*)d_in[27]; const float* bo = (const float*)d_in[28];
    const float* l1g = (const float*)d_in[29]; const float* l1b = (const float*)d_in[30];
    const float* l2g = (const float*)d_in[31]; const float* l2b = (const float*)d_in[32];
    const float* W1 = (const float*)d_in[33]; const float* bf1 = (const float*)d_in[34];
    const float* W2 = (const float*)d_in[35]; const float* bf2 = (const float*)d_in[36];

    float* ws = (float*)d_ws;
    unsigned short* d0b   = (unsigned short*)(ws);              // [8192][2048] bf16
    float*          d1raw = ws + 8388608;                       // [8192][512] f32
    unsigned short* d1b   = (unsigned short*)(ws + 12582912);   // [8192][512] bf16
    float*          xb    = ws + 14680064;                      // [8192][256] f32
    unsigned short* w1T   = (unsigned short*)(ws + 16777216);
    unsigned short* w2T   = (unsigned short*)(ws + 17301504);
    unsigned short* wuTb  = (unsigned short*)(ws + 17334272);
    unsigned short* WqkvT = (unsigned short*)(ws + 17350656);   // 8x768x256
    unsigned short* WoT   = (unsigned short*)(ws + 18137088);
    unsigned short* W1T   = (unsigned short*)(ws + 18399232);
    unsigned short* W2T   = (unsigned short*)(ws + 19447808);
    float*          b1x   = ws + 20496384;
    float*          bqkv  = ws + 20496896;
    // Phase C overlay (d0b dead after conv1 GEMM):
    unsigned short* d2b   = (unsigned short*)(ws + 1048576);    // [8192][128] bf16
    float*          ub    = ws + 1572864;                       // [8192][256] f32
    // Phase D overlay:
    unsigned short* hb    = (unsigned short*)(ws);              // [8192][256] bf16
    unsigned short* qkvb  = (unsigned short*)(ws + 1048576);    // [8192][768] bf16
    unsigned short* obb   = (unsigned short*)(ws + 4194304);    // [8192][256] bf16
    unsigned short* m1b   = (unsigned short*)(ws + 5242880);    // [8192][1024] bf16
    float* xout = (float*)d_out;

    // Weight prep: ONE launch
    k_prep_all<<<29058, 256, 0, stream>>>(w1, w2, wu, b1c, Wq, Wk, Wv, bq, bk, bv, Wo, W1, W2,
                                          w1T, w2T, wuTb, b1x, WqkvT, bqkv, WoT, W1T, W2T);

    // Encoder
    k_blur_conv0<<<8192, 256, 0, stream>>>(img, bfac, w0, b0c, g1, be1, d0b);
    k_gemm_bf16<128><<<8 * 64, 256, 0, stream>>>(d0b, w1T, b1x, nullptr, d1raw, 8, 512, 2048, 2, 0);
    k_gn2<<<4096, 256, 0, stream>>>(d1raw, g2, be2, d1b);
    k_gemm_gn<<<256, 512, 0, stream>>>(d1b, w2T, b2c, g3, be3, d2b);
    k_gemm_bf16<128><<<4 * 64, 256, 0, stream>>>(d2b, wuTb, bu, nullptr, ub, 4, 256, 128, 0, 0);
    k_lnpos<<<2048, 256, 0, stream>>>(ub, pos, lndg, lndb, lnpg, lnpb, l1g, l1b, xb, hb);

    // Transformer: per layer {qkv, attn, Wo+res+LN(l2), W1(gelu), W2+res+LN(next l1)}
    for (int i = 0; i < 8; i++) {
        k_gemm_bf16<128><<<12 * 64, 256, 0, stream>>>(hb, WqkvT + (size_t)i * 196608, bqkv + i * 768, nullptr, qkvb, 12, 768, 256, 0, 1);
        k_attn3<<<1024, 256, 0, stream>>>(qkvb, obb);
        k_gemm_ln<<<256, 512, 0, stream>>>(obb, WoT + (size_t)i * 65536, bo + i * 256, xb,
                                           l2g + i * 256, l2b + i * 256, xb, hb, 256);
        k_gemm_bf16<128><<<16 * 64, 256, 0, stream>>>(hb, W1T + (size_t)i * 262144, bf1 + i * 1024, nullptr, m1b, 16, 1024, 256, 1, 1);
        if (i < 7) {
            k_gemm_ln<<<256, 512, 0, stream>>>(m1b, W2T + (size_t)i * 262144, bf2 + i * 256, xb,
                                               l1g + (i + 1) * 256, l1b + (i + 1) * 256, xb, hb, 1024);
        } else {
            k_gemm_ln<<<256, 512, 0, stream>>>(m1b, W2T + (size_t)i * 262144, bf2 + i * 256, xb,
                                               nullptr, nullptr, xout, nullptr, 1024);
        }
    }
}